// Round 12
// baseline (205.024 us; speedup 1.0000x reference)
//
#include <hip/hip_runtime.h>

constexpr int NN = 50000;     // nodes per graph
constexpr int NE = 800000;    // edges per graph
constexpr int IND = 128;      // in dim
constexpr int HD = 256;       // hidden
constexpr int BS = 8192;      // seeds per graph
constexpr int NPAD = 50176;   // 196*256, block-aligned padded node count
constexpr int NBKT = 196;     // dst>>8 buckets per graph
constexpr int BCAP = 8192;    // capacity per bucket (mean 4096, sigma 64)

typedef __attribute__((ext_vector_type(8))) short short8v;
typedef __attribute__((ext_vector_type(4))) float floatx4;

__device__ inline ushort f2b(float f) {  // f32 -> bf16 RNE
  unsigned u = __float_as_uint(f);
  unsigned r = (u + 0x7fffu + ((u >> 16) & 1u)) >> 16;
  return (ushort)r;
}
__device__ inline float b2f(ushort b) {
  return __uint_as_float((unsigned)b << 16);
}
// accumulate both bf16 halves of a packed u32 (low elem, high elem)
__device__ __forceinline__ void acc2(unsigned u, float& a0, float& a1) {
  a0 += __uint_as_float(u << 16);
  a1 += __uint_as_float(u & 0xffff0000u);
}
__device__ inline int wave_incl_scan(int x, int lane) {
#pragma unroll
  for (int d = 1; d < 64; d <<= 1) {
    int y = __shfl_up(x, d);
    if (lane >= d) x += y;
  }
  return x;
}

// async global->LDS, 16B per lane, wave-uniform LDS base
__device__ __forceinline__ void gload16(const ushort* g, ushort* l) {
  __builtin_amdgcn_global_load_lds(
      (const __attribute__((address_space(1))) void*)g,
      (__attribute__((address_space(3))) void*)l, 16, 0, 0);
}

// ---------------- fused prep + bin + tobf16 (independent block ranges) -------
__global__ __launch_bounds__(256) void k_bin_cvt(
    const float* __restrict__ Wn1, const float* __restrict__ Ws1,
    const float* __restrict__ Wn2, const float* __restrict__ Ws2,
    ushort* __restrict__ Wt, ushort* __restrict__ Whi,
    ushort* __restrict__ Wlo, const int* __restrict__ src_i,
    const int* __restrict__ dst_i, const int* __restrict__ src_j,
    const int* __restrict__ dst_j, int* __restrict__ bcnt,
    int* __restrict__ bucketbuf, const float* __restrict__ x_i,
    const float* __restrict__ x_j, ushort* __restrict__ xb2) {
  __shared__ int hist[NBKT], gbase[NBKT], lcur[NBKT];
  const int b = blockIdx.x, t = threadIdx.x;
  if (b < 256) {  // W1 pack
    int i = b * 256 + t;
    int n = i >> 8, k = i & 255;
    float v = (k < 128) ? Wn1[k * HD + n] : Ws1[(k - 128) * HD + n];
    Wt[n * 256 + k] = f2b(v);
    return;
  }
  if (b < 768) {  // W2 hi/lo split
    int i = (b - 256) * 256 + t;
    int n = i >> 9, k = i & 511;
    float v = (k < 256) ? Wn2[k * HD + n] : Ws2[(k - 256) * HD + n];
    ushort hi = f2b(v);
    Whi[n * 512 + k] = hi;
    Wlo[n * 512 + k] = f2b(v - b2f(hi));
    return;
  }
  if (b >= 964) {  // f32 -> bf16
    int i = (b - 964) * 256 + t;
    int e4 = i * 4;
    int g = e4 >= NN * IND;
    const float* xp = g ? x_j : x_i;
    float4 v = *(const float4*)(xp + (e4 - g * NN * IND));
    ushort4 u;
    u.x = f2b(v.x); u.y = f2b(v.y); u.z = f2b(v.z); u.w = f2b(v.w);
    *(ushort4*)(xb2 + e4) = u;
    return;
  }
  // bin: blocks 768..963
  const int blk = b - 768;
  const int g = blk >= 98;
  const int c = blk - g * 98;
  const int* src = g ? src_j : src_i;
  const int* dst = g ? dst_j : dst_i;
  if (t < NBKT) hist[t] = 0;
  __syncthreads();
  const int e0 = c * 8192;
#pragma unroll
  for (int k = 0; k < 32; ++k) {
    int e = e0 + k * 256 + t;
    if (e < NE) atomicAdd(&hist[dst[e] >> 8], 1);
  }
  __syncthreads();
  if (t < NBKT) {
    int h = hist[t];
    gbase[t] = h ? atomicAdd(&bcnt[g * NBKT + t], h) : 0;
    lcur[t] = 0;
  }
  __syncthreads();
#pragma unroll
  for (int k = 0; k < 32; ++k) {
    int e = e0 + k * 256 + t;
    if (e < NE) {
      int d = dst[e];
      int bk = d >> 8;
      int p = gbase[bk] + atomicAdd(&lcur[bk], 1);
      if (p < BCAP)
        bucketbuf[(g * NBKT + bk) * BCAP + p] = (src[e] << 8) | (d & 255);
    }
  }
}

// ---------------- per-bucket CSR build (bucket-base scan inlined) ------------
__global__ __launch_bounds__(256) void k_build(const int* __restrict__ bucketbuf,
                                               const int* __restrict__ bcnt,
                                               int* __restrict__ csr,
                                               int* __restrict__ cnt2,
                                               int* __restrict__ row_start2) {
  __shared__ int hist[256], lcur[256];
  __shared__ int stage[BCAP];
  __shared__ int wtv[4];
  __shared__ int carry, tot, baseSh;
  const int b = blockIdx.x;
  const int g = b >= NBKT;
  const int bb = b - g * NBKT;
  const int t = threadIdx.x, lane = t & 63;
  if (t == 0) carry = 0;
  __syncthreads();
  for (int ch = 0; ch < 2; ++ch) {
    int i = ch * 256 + t;
    int v = (i < 2 * NBKT) ? min(bcnt[i], BCAP) : 0;
    int x = wave_incl_scan(v, lane);
    if (lane == 63) wtv[t >> 6] = x;
    __syncthreads();
    if (t == 0) {
      int run = 0;
#pragma unroll
      for (int j = 0; j < 4; ++j) { int tv = wtv[j]; wtv[j] = run; run += tv; }
      tot = run;
    }
    __syncthreads();
    if (i == b) baseSh = carry + x - v + wtv[t >> 6];
    __syncthreads();
    if (t == 0) carry += tot;
    __syncthreads();
  }
  const int base = baseSh;
  const int C = min(bcnt[b], BCAP);
  const int* buf = bucketbuf + b * BCAP;
  hist[t] = 0;
  __syncthreads();
  for (int i = t; i < C; i += 256) atomicAdd(&hist[buf[i] & 255], 1);
  __syncthreads();
  int v = hist[t];
  int x = wave_incl_scan(v, lane);
  if (lane == 63) wtv[t >> 6] = x;
  __syncthreads();
  if (t == 0) {
    int run = 0;
#pragma unroll
    for (int j = 0; j < 4; ++j) { int tv = wtv[j]; wtv[j] = run; run += tv; }
  }
  __syncthreads();
  int ls = x - v + wtv[t >> 6];
  lcur[t] = ls;
  __syncthreads();
  for (int i = t; i < C; i += 256) {
    int val = buf[i];
    int p = atomicAdd(&lcur[val & 255], 1);
    stage[p] = val >> 8;
  }
  __syncthreads();
  for (int i = t; i < C; i += 256) csr[base + i] = stage[i];
  int node = bb * 256 + t;
  cnt2[g * NPAD + node] = v;
  row_start2[g * NPAD + node] = base + ls;
}

// ---------------- layer-1 pull aggregation: 2 nodes/wave, dual-chain ILP ------
__global__ __launch_bounds__(256) void k_agg1(const ushort* __restrict__ xb2,
                                              const int* __restrict__ csr,
                                              const int* __restrict__ row_start2,
                                              const int* __restrict__ cnt2,
                                              ushort* __restrict__ aggb2) {
  int w = threadIdx.x >> 6, l = threadIdx.x & 63;
  int p = blockIdx.x * 4 + w;  // pair index, < 50000
  int nA = p * 2;              // NN even -> pair never crosses graph boundary
  int g = nA >= NN;
  int nl = nA - g * NN;
  int base = g * NPAD + nl;
  int stA = row_start2[base], degA = cnt2[base];
  int stB = row_start2[base + 1], degB = cnt2[base + 1];
  const ushort* xb = xb2 + g * NN * IND;
  float a0A = 0.f, a1A = 0.f, a0B = 0.f, a1B = 0.f;
  int cmn = min(degA, degB);
  int e = 0;
  for (; e + 4 <= cmn; e += 4) {
    int sA0 = csr[stA + e + 0], sA1 = csr[stA + e + 1];
    int sA2 = csr[stA + e + 2], sA3 = csr[stA + e + 3];
    int sB0 = csr[stB + e + 0], sB1 = csr[stB + e + 1];
    int sB2 = csr[stB + e + 2], sB3 = csr[stB + e + 3];
    unsigned uA0 = *(const unsigned*)(xb + sA0 * IND + 2 * l);
    unsigned uA1 = *(const unsigned*)(xb + sA1 * IND + 2 * l);
    unsigned uA2 = *(const unsigned*)(xb + sA2 * IND + 2 * l);
    unsigned uA3 = *(const unsigned*)(xb + sA3 * IND + 2 * l);
    unsigned uB0 = *(const unsigned*)(xb + sB0 * IND + 2 * l);
    unsigned uB1 = *(const unsigned*)(xb + sB1 * IND + 2 * l);
    unsigned uB2 = *(const unsigned*)(xb + sB2 * IND + 2 * l);
    unsigned uB3 = *(const unsigned*)(xb + sB3 * IND + 2 * l);
    acc2(uA0, a0A, a1A); acc2(uA1, a0A, a1A);
    acc2(uA2, a0A, a1A); acc2(uA3, a0A, a1A);
    acc2(uB0, a0B, a1B); acc2(uB1, a0B, a1B);
    acc2(uB2, a0B, a1B); acc2(uB3, a0B, a1B);
  }
  int eA = e, eB = e;
  for (; eA + 4 <= degA; eA += 4) {
    int s0 = csr[stA + eA + 0], s1 = csr[stA + eA + 1];
    int s2 = csr[stA + eA + 2], s3 = csr[stA + eA + 3];
    unsigned u0 = *(const unsigned*)(xb + s0 * IND + 2 * l);
    unsigned u1 = *(const unsigned*)(xb + s1 * IND + 2 * l);
    unsigned u2 = *(const unsigned*)(xb + s2 * IND + 2 * l);
    unsigned u3 = *(const unsigned*)(xb + s3 * IND + 2 * l);
    acc2(u0, a0A, a1A); acc2(u1, a0A, a1A);
    acc2(u2, a0A, a1A); acc2(u3, a0A, a1A);
  }
  for (; eA < degA; ++eA) {
    int s = csr[stA + eA];
    unsigned u = *(const unsigned*)(xb + s * IND + 2 * l);
    acc2(u, a0A, a1A);
  }
  for (; eB + 4 <= degB; eB += 4) {
    int s0 = csr[stB + eB + 0], s1 = csr[stB + eB + 1];
    int s2 = csr[stB + eB + 2], s3 = csr[stB + eB + 3];
    unsigned u0 = *(const unsigned*)(xb + s0 * IND + 2 * l);
    unsigned u1 = *(const unsigned*)(xb + s1 * IND + 2 * l);
    unsigned u2 = *(const unsigned*)(xb + s2 * IND + 2 * l);
    unsigned u3 = *(const unsigned*)(xb + s3 * IND + 2 * l);
    acc2(u0, a0B, a1B); acc2(u1, a0B, a1B);
    acc2(u2, a0B, a1B); acc2(u3, a0B, a1B);
  }
  for (; eB < degB; ++eB) {
    int s = csr[stB + eB];
    unsigned u = *(const unsigned*)(xb + s * IND + 2 * l);
    acc2(u, a0B, a1B);
  }
  float invA = 1.f / (float)max(degA, 1);
  float invB = 1.f / (float)max(degB, 1);
  ushort2 uA, uB;
  uA.x = f2b(a0A * invA); uA.y = f2b(a1A * invA);
  uB.x = f2b(a0B * invB); uB.y = f2b(a1B * invB);
  *(ushort2*)(aggb2 + (g * NN + nl) * IND + 2 * l) = uA;
  *(ushort2*)(aggb2 + (g * NN + nl + 1) * IND + 2 * l) = uB;
}

// ---------------- layer-1 MFMA GEMM: h1b = relu([agg|x] @ [Wn1;Ws1] + b1) ----
// BM=128, BN=256 (full N, A read once), BK=32; grid 784; 4 waves 2x2
__global__ __launch_bounds__(256) void k_gemm1(const ushort* __restrict__ aggb2,
                                               const ushort* __restrict__ xb2,
                                               const ushort* __restrict__ Wt,
                                               const float* __restrict__ b1,
                                               ushort* __restrict__ h1b2) {
  __shared__ ushort smem[32768];  // dbuf: A 2x4096 | B 2x8192 (48KB); epi: 128x256
  const int t = threadIdx.x;
  const int g = blockIdx.x >= 392;
  const int row0 = (blockIdx.x - g * 392) * 128;
  const ushort* aggb = aggb2 + g * NN * IND;
  const ushort* xb = xb2 + g * NN * IND;
  ushort* h1b = h1b2 + g * NN * HD;
  const int w = t >> 6, l = t & 63;
  const int wm = w & 1, wn = w >> 1;

  const int r0 = t >> 2, cs0 = t & 3;
  const int c0 = cs0 ^ (r0 & 3);
  const int rA0 = min(row0 + r0, NN - 1);
  const int rA1 = min(row0 + r0 + 64, NN - 1);
  const int gA0 = rA0 * IND + c0 * 8;
  const int gA1 = rA1 * IND + c0 * 8;
  const int gB0 = (r0 + 0) * 256 + c0 * 8;
  const int gB1 = (r0 + 64) * 256 + c0 * 8;
  const int gB2 = (r0 + 128) * 256 + c0 * 8;
  const int gB3 = (r0 + 192) * 256 + c0 * 8;
  const int wofs = w * 512;

  floatx4 acc[4][8];
#pragma unroll
  for (int i = 0; i < 4; ++i)
#pragma unroll
    for (int j = 0; j < 8; ++j) acc[i][j] = (floatx4){0.f, 0.f, 0.f, 0.f};

#define STAGE(buf, kk)                                                      \
  do {                                                                      \
    const ushort* Ab = ((kk) < 128) ? (aggb + (kk)) : (xb + ((kk) - 128));  \
    ushort* Ald = smem + (buf) * 4096;                                      \
    ushort* Bld = smem + 8192 + (buf) * 8192;                               \
    gload16(Ab + gA0, Ald + wofs);                                          \
    gload16(Ab + gA1, Ald + 2048 + wofs);                                   \
    gload16(Wt + gB0 + (kk), Bld + wofs);                                   \
    gload16(Wt + gB1 + (kk), Bld + 2048 + wofs);                            \
    gload16(Wt + gB2 + (kk), Bld + 4096 + wofs);                            \
    gload16(Wt + gB3 + (kk), Bld + 6144 + wofs);                            \
  } while (0)

  STAGE(0, 0);
  __syncthreads();
  int cur = 0;
  const int rA = l & 15, gg = l >> 4;
  for (int step = 0; step < 8; ++step) {
    if (step < 7) STAGE(cur ^ 1, (step + 1) * 32);
    const ushort* Abuf = smem + cur * 4096;
    const ushort* Bbuf = smem + 8192 + cur * 8192;
    short8v af[4], bf[8];
#pragma unroll
    for (int i = 0; i < 4; ++i) {
      int r = wm * 64 + i * 16 + rA;
      af[i] = *(const short8v*)(Abuf + r * 32 + ((gg ^ (r & 3)) * 8));
    }
#pragma unroll
    for (int j = 0; j < 8; ++j) {
      int r = wn * 128 + j * 16 + rA;
      bf[j] = *(const short8v*)(Bbuf + r * 32 + ((gg ^ (r & 3)) * 8));
    }
#pragma unroll
    for (int i = 0; i < 4; ++i)
#pragma unroll
      for (int j = 0; j < 8; ++j)
        acc[i][j] = __builtin_amdgcn_mfma_f32_16x16x32_bf16(af[i], bf[j],
                                                            acc[i][j], 0, 0, 0);
    if (step < 7) {
      __syncthreads();
      cur ^= 1;
    }
  }
#undef STAGE

  // epilogue: acc -> bf16 LDS tile [128][256], then coalesced row stores
  __syncthreads();
  const int rD = l >> 4, cD = l & 15;
#pragma unroll
  for (int j = 0; j < 8; ++j) {
    int cl = wn * 128 + j * 16 + cD;
    float bias = b1[cl];
#pragma unroll
    for (int i = 0; i < 4; ++i) {
      int rbase = wm * 64 + i * 16 + rD * 4;
#pragma unroll
      for (int rr = 0; rr < 4; ++rr)
        smem[(rbase + rr) * 256 + cl] = f2b(fmaxf(acc[i][j][rr] + bias, 0.f));
    }
  }
  __syncthreads();
  const int rl = t >> 5, ch = t & 31;
#pragma unroll
  for (int it = 0; it < 16; ++it) {
    int row_l = rl + it * 8;
    int grow = row0 + row_l;
    if (grow < NN)
      *(short8v*)(h1b + grow * HD + ch * 8) =
          *(const short8v*)(smem + row_l * 256 + ch * 8);
  }
}

// ---------------- layer-2 aggregation @ seeds: half-wave, 2 edges/instr ------
__global__ __launch_bounds__(256) void k_agg2(
    const ushort* __restrict__ h1b2, const int* __restrict__ csr,
    const int* __restrict__ row_start2, const int* __restrict__ cnt2,
    const int* __restrict__ ids_i, const int* __restrict__ ids_j,
    ushort* __restrict__ A2) {
  __shared__ float red[4][HD];
  const int b = blockIdx.x;
  const int g = b >= BS;
  const int node = (g ? ids_j : ids_i)[b - g * BS];
  const int st = row_start2[g * NPAD + node], deg = cnt2[g * NPAD + node];
  const ushort* h1b = h1b2 + g * NN * HD;
  const int w = threadIdx.x >> 6, l = threadIdx.x & 63;
  const int h = l >> 5, c = l & 31;
  float a0 = 0.f, a1 = 0.f, a2 = 0.f, a3 = 0.f;
  float a4 = 0.f, a5 = 0.f, a6 = 0.f, a7 = 0.f;
  int e = w * 2 + h;
  for (; e + 8 < deg; e += 16) {
    int s0 = csr[st + e], s1 = csr[st + e + 8];
    uint4 u0 = *(const uint4*)(h1b + s0 * HD + c * 8);
    uint4 u1 = *(const uint4*)(h1b + s1 * HD + c * 8);
    acc2(u0.x, a0, a1); acc2(u0.y, a2, a3);
    acc2(u0.z, a4, a5); acc2(u0.w, a6, a7);
    acc2(u1.x, a0, a1); acc2(u1.y, a2, a3);
    acc2(u1.z, a4, a5); acc2(u1.w, a6, a7);
  }
  if (e < deg) {
    int s = csr[st + e];
    uint4 u = *(const uint4*)(h1b + s * HD + c * 8);
    acc2(u.x, a0, a1); acc2(u.y, a2, a3);
    acc2(u.z, a4, a5); acc2(u.w, a6, a7);
  }
  a0 += __shfl_xor(a0, 32); a1 += __shfl_xor(a1, 32);
  a2 += __shfl_xor(a2, 32); a3 += __shfl_xor(a3, 32);
  a4 += __shfl_xor(a4, 32); a5 += __shfl_xor(a5, 32);
  a6 += __shfl_xor(a6, 32); a7 += __shfl_xor(a7, 32);
  if (h == 0) {
    *(float4*)&red[w][c * 8] = (float4){a0, a1, a2, a3};
    *(float4*)&red[w][c * 8 + 4] = (float4){a4, a5, a6, a7};
  }
  __syncthreads();
  const int t = threadIdx.x;
  float s = (red[0][t] + red[1][t]) + (red[2][t] + red[3][t]);
  s *= 1.f / (float)max(deg, 1);
  A2[b * 512 + t] = f2b(s);
  A2[b * 512 + 256 + t] = h1b[node * HD + t];  // exact bf16 copy
}

// ---------------- layer-2 MFMA GEMM + fused l2norm/dot + combine -> out ------
// 128 rows/block = 64 seeds x both graph halves; K=512; grid 128
__global__ __launch_bounds__(256) void k_head(const ushort* __restrict__ A2,
                                              const ushort* __restrict__ Whi,
                                              const ushort* __restrict__ Wlo,
                                              const float* __restrict__ b2,
                                              const float* __restrict__ W_out,
                                              const float* __restrict__ b_out,
                                              float* __restrict__ out) {
  __shared__ ushort Ahl[128 * 32];
  __shared__ ushort Bhl[256 * 32];
  __shared__ ushort Bll[256 * 32];
  __shared__ float sred[4][128][2];
  const int t = threadIdx.x;
  const int sb = blockIdx.x * 64;  // seed base, 0..8128
  const int w = t >> 6, l = t & 63;
  floatx4 acc[8][4];
#pragma unroll
  for (int i = 0; i < 8; ++i)
#pragma unroll
    for (int j = 0; j < 4; ++j) acc[i][j] = (floatx4){0.f, 0.f, 0.f, 0.f};

  for (int kk = 0; kk < 512; kk += 32) {
#pragma unroll
    for (int s = t; s < 512; s += 256) {  // A: 128 rows x 4 chunks
      int r = s >> 2, c = s & 3;
      int sw = (c ^ (r & 3)) * 8;
      int arow = (r < 64) ? (sb + r) : (BS + sb + r - 64);
      *(short8v*)(Ahl + r * 32 + sw) =
          *(const short8v*)(A2 + arow * 512 + kk + c * 8);
    }
#pragma unroll
    for (int s = t; s < 1024; s += 256) {  // B: 256 cols x 4 chunks
      int r = s >> 2, c = s & 3;
      int sw = (c ^ (r & 3)) * 8;
      *(short8v*)(Bhl + r * 32 + sw) =
          *(const short8v*)(Whi + r * 512 + kk + c * 8);
      *(short8v*)(Bll + r * 32 + sw) =
          *(const short8v*)(Wlo + r * 512 + kk + c * 8);
    }
    __syncthreads();
    const int rA = l & 15, gg = l >> 4;
    short8v af[8], bh[4], bl[4];
#pragma unroll
    for (int i = 0; i < 8; ++i) {
      int r = i * 16 + rA;
      af[i] = *(const short8v*)(Ahl + r * 32 + ((gg ^ (r & 3)) * 8));
    }
#pragma unroll
    for (int j = 0; j < 4; ++j) {
      int r = w * 64 + j * 16 + rA;
      int sw = (gg ^ (r & 3)) * 8;
      bh[j] = *(const short8v*)(Bhl + r * 32 + sw);
      bl[j] = *(const short8v*)(Bll + r * 32 + sw);
    }
#pragma unroll
    for (int i = 0; i < 8; ++i)
#pragma unroll
      for (int j = 0; j < 4; ++j) {
        acc[i][j] = __builtin_amdgcn_mfma_f32_16x16x32_bf16(af[i], bh[j],
                                                            acc[i][j], 0, 0, 0);
        acc[i][j] = __builtin_amdgcn_mfma_f32_16x16x32_bf16(af[i], bl[j],
                                                            acc[i][j], 0, 0, 0);
      }
    __syncthreads();
  }
  // epilogue: bias, per-row ss/dp, 16-lane shuffle reduce
  const int cD = l & 15, rD = l >> 4;
  float bj[4], wo0[4], wo1[4];
#pragma unroll
  for (int j = 0; j < 4; ++j) {
    int col = w * 64 + j * 16 + cD;
    bj[j] = b2[col];
    wo0[j] = W_out[col];
    wo1[j] = W_out[256 + col];
  }
#pragma unroll
  for (int i = 0; i < 8; ++i) {
    const bool hj = (i >= 4);  // rows 64..127 = graph-j half
#pragma unroll
    for (int rr = 0; rr < 4; ++rr) {
      float ssv = 0.f, dpv = 0.f;
#pragma unroll
      for (int j = 0; j < 4; ++j) {
        float v = acc[i][j][rr] + bj[j];
        ssv += v * v;
        dpv += v * (hj ? wo1[j] : wo0[j]);
      }
#pragma unroll
      for (int d = 1; d < 16; d <<= 1) {
        ssv += __shfl_xor(ssv, d);
        dpv += __shfl_xor(dpv, d);
      }
      if (cD == 0) {
        int row = i * 16 + rD * 4 + rr;
        sred[w][row][0] = ssv;
        sred[w][row][1] = dpv;
      }
    }
  }
  __syncthreads();
  if (t < 64) {
    float ssi = (sred[0][t][0] + sred[1][t][0]) + (sred[2][t][0] + sred[3][t][0]);
    float dpi = (sred[0][t][1] + sred[1][t][1]) + (sred[2][t][1] + sred[3][t][1]);
    int tj = t + 64;
    float ssj = (sred[0][tj][0] + sred[1][tj][0]) + (sred[2][tj][0] + sred[3][tj][0]);
    float dpj = (sred[0][tj][1] + sred[1][tj][1]) + (sred[2][tj][1] + sred[3][tj][1]);
    out[sb + t] = dpi / fmaxf(sqrtf(ssi), 1e-12f) +
                  dpj / fmaxf(sqrtf(ssj), 1e-12f) + b_out[0];
  }
}

extern "C" void kernel_launch(void* const* d_in, const int* in_sizes, int n_in,
                              void* d_out, int out_size, void* d_ws,
                              size_t ws_size, hipStream_t stream) {
  (void)in_sizes; (void)n_in; (void)out_size; (void)ws_size;
  const float* x_i = (const float*)d_in[0];
  const float* x_j = (const float*)d_in[1];
  const int* src_i = (const int*)d_in[2];
  const int* dst_i = (const int*)d_in[3];
  const int* src_j = (const int*)d_in[4];
  const int* dst_j = (const int*)d_in[5];
  const int* ids_i = (const int*)d_in[6];
  const int* ids_j = (const int*)d_in[7];
  const float* Wn1 = (const float*)d_in[8];
  const float* Ws1 = (const float*)d_in[9];
  const float* b1 = (const float*)d_in[10];
  const float* Wn2 = (const float*)d_in[11];
  const float* Ws2 = (const float*)d_in[12];
  const float* b2 = (const float*)d_in[13];
  const float* W_out = (const float*)d_in[14];
  const float* b_out = (const float*)d_in[15];
  float* out = (float*)d_out;

  char* w = (char*)d_ws;
  int* bcnt       = (int*)(w + 0);            // 1,568
  int* cnt2       = (int*)(w + 4096);         // 401,408
  int* row_start2 = (int*)(w + 405504);       // 401,408
  int* bucketbuf  = (int*)(w + 806912);       // 12,845,056 -> 13,651,968
  ushort* Wt      = (ushort*)(w + 13651968);  // 131,072
  ushort* W2hi    = (ushort*)(w + 13783040);  // 262,144
  ushort* W2lo    = (ushort*)(w + 14045184);  // 262,144
  ushort* xb2     = (ushort*)(w + 14307328);  // 25,600,000 -> 39,907,328
  ushort* aggb2   = (ushort*)(w + 39907328);  // 25,600,000 -> 65,507,328
  ushort* h1b2    = (ushort*)(w + 65507328);  // 51,200,000 -> 116,707,328
  int* csr        = (int*)(w + 116707328);    // 6,400,000 -> 123,107,328
  // alias over xb2 (dead after k_gemm1):
  ushort* A2      = (ushort*)(w + 14307328);  // 16,777,216 -> 31,084,544

  hipMemsetAsync(bcnt, 0, 2 * NBKT * sizeof(int), stream);
  k_bin_cvt<<<13464, 256, 0, stream>>>(Wn1, Ws1, Wn2, Ws2, Wt, W2hi, W2lo,
                                       src_i, dst_i, src_j, dst_j, bcnt,
                                       bucketbuf, x_i, x_j, xb2);
  k_build<<<392, 256, 0, stream>>>(bucketbuf, bcnt, csr, cnt2, row_start2);
  k_agg1<<<12500, 256, 0, stream>>>(xb2, csr, row_start2, cnt2, aggb2);
  k_gemm1<<<784, 256, 0, stream>>>(aggb2, xb2, Wt, b1, h1b2);
  k_agg2<<<2 * BS, 256, 0, stream>>>(h1b2, csr, row_start2, cnt2, ids_i, ids_j,
                                     A2);
  k_head<<<128, 256, 0, stream>>>(A2, W2hi, W2lo, b2, W_out, b_out, out);
}

// Round 13
// 198.579 us; speedup vs baseline: 1.0325x; 1.0325x over previous
//
#include <hip/hip_runtime.h>

constexpr int NN = 50000;     // nodes per graph
constexpr int NE = 800000;    // edges per graph
constexpr int IND = 128;      // in dim
constexpr int HD = 256;       // hidden
constexpr int BS = 8192;      // seeds per graph
constexpr int NPAD = 50176;   // 196*256, block-aligned padded node count
constexpr int NBKT = 196;     // dst>>8 buckets per graph
constexpr int BCAP = 8192;    // capacity per bucket (mean 4096, sigma 64)

typedef __attribute__((ext_vector_type(8))) short short8v;
typedef __attribute__((ext_vector_type(4))) float floatx4;

__device__ inline ushort f2b(float f) {  // f32 -> bf16 RNE
  unsigned u = __float_as_uint(f);
  unsigned r = (u + 0x7fffu + ((u >> 16) & 1u)) >> 16;
  return (ushort)r;
}
__device__ inline float b2f(ushort b) {
  return __uint_as_float((unsigned)b << 16);
}
// accumulate both bf16 halves of a packed u32 (low elem, high elem)
__device__ __forceinline__ void acc2(unsigned u, float& a0, float& a1) {
  a0 += __uint_as_float(u << 16);
  a1 += __uint_as_float(u & 0xffff0000u);
}
__device__ inline int wave_incl_scan(int x, int lane) {
#pragma unroll
  for (int d = 1; d < 64; d <<= 1) {
    int y = __shfl_up(x, d);
    if (lane >= d) x += y;
  }
  return x;
}

// async global->LDS, 16B per lane, wave-uniform LDS base
__device__ __forceinline__ void gload16(const ushort* g, ushort* l) {
  __builtin_amdgcn_global_load_lds(
      (const __attribute__((address_space(1))) void*)g,
      (__attribute__((address_space(3))) void*)l, 16, 0, 0);
}

// ---------------- k1: W-prep + edge binning ----------------
// blocks [0,256): pack Wt; [256,768): split W2 hi/lo; [768,964): bin edges
__global__ __launch_bounds__(256) void k_prep_bin(
    const float* __restrict__ Wn1, const float* __restrict__ Ws1,
    const float* __restrict__ Wn2, const float* __restrict__ Ws2,
    ushort* __restrict__ Wt, ushort* __restrict__ Whi,
    ushort* __restrict__ Wlo, const int* __restrict__ src_i,
    const int* __restrict__ dst_i, const int* __restrict__ src_j,
    const int* __restrict__ dst_j, int* __restrict__ bcnt,
    int* __restrict__ bucketbuf) {
  __shared__ int hist[NBKT], gbase[NBKT], lcur[NBKT];
  const int b = blockIdx.x, t = threadIdx.x;
  if (b < 256) {  // W1 pack
    int i = b * 256 + t;
    int n = i >> 8, k = i & 255;
    float v = (k < 128) ? Wn1[k * HD + n] : Ws1[(k - 128) * HD + n];
    Wt[n * 256 + k] = f2b(v);
    return;
  }
  if (b < 768) {  // W2 hi/lo split
    int i = (b - 256) * 256 + t;
    int n = i >> 9, k = i & 511;
    float v = (k < 256) ? Wn2[k * HD + n] : Ws2[(k - 256) * HD + n];
    ushort hi = f2b(v);
    Whi[n * 512 + k] = hi;
    Wlo[n * 512 + k] = f2b(v - b2f(hi));
    return;
  }
  // bin: blocks 768..963
  const int blk = b - 768;
  const int g = blk >= 98;
  const int c = blk - g * 98;
  const int* src = g ? src_j : src_i;
  const int* dst = g ? dst_j : dst_i;
  if (t < NBKT) hist[t] = 0;
  __syncthreads();
  const int e0 = c * 8192;
#pragma unroll
  for (int k = 0; k < 32; ++k) {
    int e = e0 + k * 256 + t;
    if (e < NE) atomicAdd(&hist[dst[e] >> 8], 1);
  }
  __syncthreads();
  if (t < NBKT) {
    int h = hist[t];
    gbase[t] = h ? atomicAdd(&bcnt[g * NBKT + t], h) : 0;
    lcur[t] = 0;
  }
  __syncthreads();
#pragma unroll
  for (int k = 0; k < 32; ++k) {
    int e = e0 + k * 256 + t;
    if (e < NE) {
      int d = dst[e];
      int bk = d >> 8;
      int p = gbase[bk] + atomicAdd(&lcur[bk], 1);
      if (p < BCAP)
        bucketbuf[(g * NBKT + bk) * BCAP + p] = (src[e] << 8) | (d & 255);
    }
  }
}

// ---------------- k2: CSR build (blocks 0..391) + f32->bf16 cvt (rest) -------
__global__ __launch_bounds__(256) void k_build_cvt(
    const int* __restrict__ bucketbuf, const int* __restrict__ bcnt,
    int* __restrict__ csr, int* __restrict__ cnt2,
    int* __restrict__ row_start2, const float* __restrict__ x_i,
    const float* __restrict__ x_j, ushort* __restrict__ xb2) {
  __shared__ int hist[256], lcur[256];
  __shared__ int stage[BCAP];
  __shared__ int wtv[4];
  __shared__ int carry, tot, baseSh;
  const int blk = blockIdx.x;
  const int t = threadIdx.x, lane = t & 63;
  if (blk >= 392) {  // f32 -> bf16 convert
    int i = (blk - 392) * 256 + t;
    int e4 = i * 4;
    int g = e4 >= NN * IND;
    const float* xp = g ? x_j : x_i;
    float4 v = *(const float4*)(xp + (e4 - g * NN * IND));
    ushort4 u;
    u.x = f2b(v.x); u.y = f2b(v.y); u.z = f2b(v.z); u.w = f2b(v.w);
    *(ushort4*)(xb2 + e4) = u;
    return;
  }
  const int b = blk;
  const int g = b >= NBKT;
  const int bb = b - g * NBKT;
  if (t == 0) carry = 0;
  __syncthreads();
  for (int ch = 0; ch < 2; ++ch) {
    int i = ch * 256 + t;
    int v = (i < 2 * NBKT) ? min(bcnt[i], BCAP) : 0;
    int x = wave_incl_scan(v, lane);
    if (lane == 63) wtv[t >> 6] = x;
    __syncthreads();
    if (t == 0) {
      int run = 0;
#pragma unroll
      for (int j = 0; j < 4; ++j) { int tv = wtv[j]; wtv[j] = run; run += tv; }
      tot = run;
    }
    __syncthreads();
    if (i == b) baseSh = carry + x - v + wtv[t >> 6];
    __syncthreads();
    if (t == 0) carry += tot;
    __syncthreads();
  }
  const int base = baseSh;
  const int C = min(bcnt[b], BCAP);
  const int* buf = bucketbuf + b * BCAP;
  hist[t] = 0;
  __syncthreads();
  for (int i = t; i < C; i += 256) atomicAdd(&hist[buf[i] & 255], 1);
  __syncthreads();
  int v = hist[t];
  int x = wave_incl_scan(v, lane);
  if (lane == 63) wtv[t >> 6] = x;
  __syncthreads();
  if (t == 0) {
    int run = 0;
#pragma unroll
    for (int j = 0; j < 4; ++j) { int tv = wtv[j]; wtv[j] = run; run += tv; }
  }
  __syncthreads();
  int ls = x - v + wtv[t >> 6];
  lcur[t] = ls;
  __syncthreads();
  for (int i = t; i < C; i += 256) {
    int val = buf[i];
    int p = atomicAdd(&lcur[val & 255], 1);
    stage[p] = val >> 8;
  }
  __syncthreads();
  for (int i = t; i < C; i += 256) csr[base + i] = stage[i];
  int node = bb * 256 + t;
  cnt2[g * NPAD + node] = v;
  row_start2[g * NPAD + node] = base + ls;
}

// ---------------- layer-1 pull aggregation: 2 nodes/wave, dual-chain ILP ------
__global__ __launch_bounds__(256) void k_agg1(const ushort* __restrict__ xb2,
                                              const int* __restrict__ csr,
                                              const int* __restrict__ row_start2,
                                              const int* __restrict__ cnt2,
                                              ushort* __restrict__ aggb2) {
  int w = threadIdx.x >> 6, l = threadIdx.x & 63;
  int p = blockIdx.x * 4 + w;  // pair index, < 50000
  int nA = p * 2;              // NN even -> pair never crosses graph boundary
  int g = nA >= NN;
  int nl = nA - g * NN;
  int base = g * NPAD + nl;
  int stA = row_start2[base], degA = cnt2[base];
  int stB = row_start2[base + 1], degB = cnt2[base + 1];
  const ushort* xb = xb2 + g * NN * IND;
  float a0A = 0.f, a1A = 0.f, a0B = 0.f, a1B = 0.f;
  int cmn = min(degA, degB);
  int e = 0;
  for (; e + 4 <= cmn; e += 4) {
    int sA0 = csr[stA + e + 0], sA1 = csr[stA + e + 1];
    int sA2 = csr[stA + e + 2], sA3 = csr[stA + e + 3];
    int sB0 = csr[stB + e + 0], sB1 = csr[stB + e + 1];
    int sB2 = csr[stB + e + 2], sB3 = csr[stB + e + 3];
    unsigned uA0 = *(const unsigned*)(xb + sA0 * IND + 2 * l);
    unsigned uA1 = *(const unsigned*)(xb + sA1 * IND + 2 * l);
    unsigned uA2 = *(const unsigned*)(xb + sA2 * IND + 2 * l);
    unsigned uA3 = *(const unsigned*)(xb + sA3 * IND + 2 * l);
    unsigned uB0 = *(const unsigned*)(xb + sB0 * IND + 2 * l);
    unsigned uB1 = *(const unsigned*)(xb + sB1 * IND + 2 * l);
    unsigned uB2 = *(const unsigned*)(xb + sB2 * IND + 2 * l);
    unsigned uB3 = *(const unsigned*)(xb + sB3 * IND + 2 * l);
    acc2(uA0, a0A, a1A); acc2(uA1, a0A, a1A);
    acc2(uA2, a0A, a1A); acc2(uA3, a0A, a1A);
    acc2(uB0, a0B, a1B); acc2(uB1, a0B, a1B);
    acc2(uB2, a0B, a1B); acc2(uB3, a0B, a1B);
  }
  int eA = e, eB = e;
  for (; eA + 4 <= degA; eA += 4) {
    int s0 = csr[stA + eA + 0], s1 = csr[stA + eA + 1];
    int s2 = csr[stA + eA + 2], s3 = csr[stA + eA + 3];
    unsigned u0 = *(const unsigned*)(xb + s0 * IND + 2 * l);
    unsigned u1 = *(const unsigned*)(xb + s1 * IND + 2 * l);
    unsigned u2 = *(const unsigned*)(xb + s2 * IND + 2 * l);
    unsigned u3 = *(const unsigned*)(xb + s3 * IND + 2 * l);
    acc2(u0, a0A, a1A); acc2(u1, a0A, a1A);
    acc2(u2, a0A, a1A); acc2(u3, a0A, a1A);
  }
  for (; eA < degA; ++eA) {
    int s = csr[stA + eA];
    unsigned u = *(const unsigned*)(xb + s * IND + 2 * l);
    acc2(u, a0A, a1A);
  }
  for (; eB + 4 <= degB; eB += 4) {
    int s0 = csr[stB + eB + 0], s1 = csr[stB + eB + 1];
    int s2 = csr[stB + eB + 2], s3 = csr[stB + eB + 3];
    unsigned u0 = *(const unsigned*)(xb + s0 * IND + 2 * l);
    unsigned u1 = *(const unsigned*)(xb + s1 * IND + 2 * l);
    unsigned u2 = *(const unsigned*)(xb + s2 * IND + 2 * l);
    unsigned u3 = *(const unsigned*)(xb + s3 * IND + 2 * l);
    acc2(u0, a0B, a1B); acc2(u1, a0B, a1B);
    acc2(u2, a0B, a1B); acc2(u3, a0B, a1B);
  }
  for (; eB < degB; ++eB) {
    int s = csr[stB + eB];
    unsigned u = *(const unsigned*)(xb + s * IND + 2 * l);
    acc2(u, a0B, a1B);
  }
  float invA = 1.f / (float)max(degA, 1);
  float invB = 1.f / (float)max(degB, 1);
  ushort2 uA, uB;
  uA.x = f2b(a0A * invA); uA.y = f2b(a1A * invA);
  uB.x = f2b(a0B * invB); uB.y = f2b(a1B * invB);
  *(ushort2*)(aggb2 + (g * NN + nl) * IND + 2 * l) = uA;
  *(ushort2*)(aggb2 + (g * NN + nl + 1) * IND + 2 * l) = uB;
}

// ---------------- layer-1 MFMA GEMM: h1b = relu([agg|x] @ [Wn1;Ws1] + b1) ----
// BM=128, BN=256 (full N, A read once), BK=32; grid 784; 4 waves 2x2
__global__ __launch_bounds__(256) void k_gemm1(const ushort* __restrict__ aggb2,
                                               const ushort* __restrict__ xb2,
                                               const ushort* __restrict__ Wt,
                                               const float* __restrict__ b1,
                                               ushort* __restrict__ h1b2) {
  __shared__ ushort smem[32768];  // dbuf: A 2x4096 | B 2x8192 (48KB); epi: 128x256
  const int t = threadIdx.x;
  const int g = blockIdx.x >= 392;
  const int row0 = (blockIdx.x - g * 392) * 128;
  const ushort* aggb = aggb2 + g * NN * IND;
  const ushort* xb = xb2 + g * NN * IND;
  ushort* h1b = h1b2 + g * NN * HD;
  const int w = t >> 6, l = t & 63;
  const int wm = w & 1, wn = w >> 1;

  const int r0 = t >> 2, cs0 = t & 3;
  const int c0 = cs0 ^ (r0 & 3);
  const int rA0 = min(row0 + r0, NN - 1);
  const int rA1 = min(row0 + r0 + 64, NN - 1);
  const int gA0 = rA0 * IND + c0 * 8;
  const int gA1 = rA1 * IND + c0 * 8;
  const int gB0 = (r0 + 0) * 256 + c0 * 8;
  const int gB1 = (r0 + 64) * 256 + c0 * 8;
  const int gB2 = (r0 + 128) * 256 + c0 * 8;
  const int gB3 = (r0 + 192) * 256 + c0 * 8;
  const int wofs = w * 512;

  floatx4 acc[4][8];
#pragma unroll
  for (int i = 0; i < 4; ++i)
#pragma unroll
    for (int j = 0; j < 8; ++j) acc[i][j] = (floatx4){0.f, 0.f, 0.f, 0.f};

#define STAGE(buf, kk)                                                      \
  do {                                                                      \
    const ushort* Ab = ((kk) < 128) ? (aggb + (kk)) : (xb + ((kk) - 128));  \
    ushort* Ald = smem + (buf) * 4096;                                      \
    ushort* Bld = smem + 8192 + (buf) * 8192;                               \
    gload16(Ab + gA0, Ald + wofs);                                          \
    gload16(Ab + gA1, Ald + 2048 + wofs);                                   \
    gload16(Wt + gB0 + (kk), Bld + wofs);                                   \
    gload16(Wt + gB1 + (kk), Bld + 2048 + wofs);                            \
    gload16(Wt + gB2 + (kk), Bld + 4096 + wofs);                            \
    gload16(Wt + gB3 + (kk), Bld + 6144 + wofs);                            \
  } while (0)

  STAGE(0, 0);
  __syncthreads();
  int cur = 0;
  const int rA = l & 15, gg = l >> 4;
  for (int step = 0; step < 8; ++step) {
    if (step < 7) STAGE(cur ^ 1, (step + 1) * 32);
    const ushort* Abuf = smem + cur * 4096;
    const ushort* Bbuf = smem + 8192 + cur * 8192;
    short8v af[4], bf[8];
#pragma unroll
    for (int i = 0; i < 4; ++i) {
      int r = wm * 64 + i * 16 + rA;
      af[i] = *(const short8v*)(Abuf + r * 32 + ((gg ^ (r & 3)) * 8));
    }
#pragma unroll
    for (int j = 0; j < 8; ++j) {
      int r = wn * 128 + j * 16 + rA;
      bf[j] = *(const short8v*)(Bbuf + r * 32 + ((gg ^ (r & 3)) * 8));
    }
#pragma unroll
    for (int i = 0; i < 4; ++i)
#pragma unroll
      for (int j = 0; j < 8; ++j)
        acc[i][j] = __builtin_amdgcn_mfma_f32_16x16x32_bf16(af[i], bf[j],
                                                            acc[i][j], 0, 0, 0);
    if (step < 7) {
      __syncthreads();
      cur ^= 1;
    }
  }
#undef STAGE

  // epilogue: acc -> bf16 LDS tile [128][256], then coalesced row stores
  __syncthreads();
  const int rD = l >> 4, cD = l & 15;
#pragma unroll
  for (int j = 0; j < 8; ++j) {
    int cl = wn * 128 + j * 16 + cD;
    float bias = b1[cl];
#pragma unroll
    for (int i = 0; i < 4; ++i) {
      int rbase = wm * 64 + i * 16 + rD * 4;
#pragma unroll
      for (int rr = 0; rr < 4; ++rr)
        smem[(rbase + rr) * 256 + cl] = f2b(fmaxf(acc[i][j][rr] + bias, 0.f));
    }
  }
  __syncthreads();
  const int rl = t >> 5, ch = t & 31;
#pragma unroll
  for (int it = 0; it < 16; ++it) {
    int row_l = rl + it * 8;
    int grow = row0 + row_l;
    if (grow < NN)
      *(short8v*)(h1b + grow * HD + ch * 8) =
          *(const short8v*)(smem + row_l * 256 + ch * 8);
  }
}

// ---------------- layer-2 aggregation @ seeds: half-wave, 2 edges/instr ------
__global__ __launch_bounds__(256) void k_agg2(
    const ushort* __restrict__ h1b2, const int* __restrict__ csr,
    const int* __restrict__ row_start2, const int* __restrict__ cnt2,
    const int* __restrict__ ids_i, const int* __restrict__ ids_j,
    ushort* __restrict__ A2) {
  __shared__ float red[4][HD];
  const int b = blockIdx.x;
  const int g = b >= BS;
  const int node = (g ? ids_j : ids_i)[b - g * BS];
  const int st = row_start2[g * NPAD + node], deg = cnt2[g * NPAD + node];
  const ushort* h1b = h1b2 + g * NN * HD;
  const int w = threadIdx.x >> 6, l = threadIdx.x & 63;
  const int h = l >> 5, c = l & 31;
  float a0 = 0.f, a1 = 0.f, a2 = 0.f, a3 = 0.f;
  float a4 = 0.f, a5 = 0.f, a6 = 0.f, a7 = 0.f;
  int e = w * 2 + h;
  for (; e + 8 < deg; e += 16) {
    int s0 = csr[st + e], s1 = csr[st + e + 8];
    uint4 u0 = *(const uint4*)(h1b + s0 * HD + c * 8);
    uint4 u1 = *(const uint4*)(h1b + s1 * HD + c * 8);
    acc2(u0.x, a0, a1); acc2(u0.y, a2, a3);
    acc2(u0.z, a4, a5); acc2(u0.w, a6, a7);
    acc2(u1.x, a0, a1); acc2(u1.y, a2, a3);
    acc2(u1.z, a4, a5); acc2(u1.w, a6, a7);
  }
  if (e < deg) {
    int s = csr[st + e];
    uint4 u = *(const uint4*)(h1b + s * HD + c * 8);
    acc2(u.x, a0, a1); acc2(u.y, a2, a3);
    acc2(u.z, a4, a5); acc2(u.w, a6, a7);
  }
  a0 += __shfl_xor(a0, 32); a1 += __shfl_xor(a1, 32);
  a2 += __shfl_xor(a2, 32); a3 += __shfl_xor(a3, 32);
  a4 += __shfl_xor(a4, 32); a5 += __shfl_xor(a5, 32);
  a6 += __shfl_xor(a6, 32); a7 += __shfl_xor(a7, 32);
  if (h == 0) {
    *(float4*)&red[w][c * 8] = (float4){a0, a1, a2, a3};
    *(float4*)&red[w][c * 8 + 4] = (float4){a4, a5, a6, a7};
  }
  __syncthreads();
  const int t = threadIdx.x;
  float s = (red[0][t] + red[1][t]) + (red[2][t] + red[3][t]);
  s *= 1.f / (float)max(deg, 1);
  A2[b * 512 + t] = f2b(s);
  A2[b * 512 + 256 + t] = h1b[node * HD + t];  // exact bf16 copy
}

// ---------------- layer-2 MFMA GEMM + fused l2norm/dot -> outP --------------
// 64 rows x 256 cols per block, K=512; grid 256
__global__ __launch_bounds__(256) void k_head(const ushort* __restrict__ A2,
                                              const ushort* __restrict__ Whi,
                                              const ushort* __restrict__ Wlo,
                                              const float* __restrict__ b2,
                                              const float* __restrict__ W_out,
                                              float* __restrict__ outP) {
  __shared__ ushort Ahl[64 * 32];
  __shared__ ushort Bhl[256 * 32];
  __shared__ ushort Bll[256 * 32];
  __shared__ float sred[4][64][2];
  const int t = threadIdx.x;
  const int row0 = blockIdx.x * 64;
  const int w = t >> 6, l = t & 63;
  const int woff = (row0 >= BS) ? 256 : 0;
  floatx4 acc[4][4];
#pragma unroll
  for (int i = 0; i < 4; ++i)
#pragma unroll
    for (int j = 0; j < 4; ++j) acc[i][j] = (floatx4){0.f, 0.f, 0.f, 0.f};

  for (int kk = 0; kk < 512; kk += 32) {
    {
      int r = t >> 2, c = t & 3;
      int sw = (c ^ (r & 3)) * 8;
      *(short8v*)(Ahl + r * 32 + sw) =
          *(const short8v*)(A2 + (row0 + r) * 512 + kk + c * 8);
    }
#pragma unroll
    for (int s = t; s < 1024; s += 256) {
      int r = s >> 2, c = s & 3;
      int sw = (c ^ (r & 3)) * 8;
      *(short8v*)(Bhl + r * 32 + sw) =
          *(const short8v*)(Whi + r * 512 + kk + c * 8);
      *(short8v*)(Bll + r * 32 + sw) =
          *(const short8v*)(Wlo + r * 512 + kk + c * 8);
    }
    __syncthreads();
    const int rA = l & 15, gg = l >> 4;
    short8v af[4], bh[4], bl[4];
#pragma unroll
    for (int i = 0; i < 4; ++i) {
      int r = i * 16 + rA;
      af[i] = *(const short8v*)(Ahl + r * 32 + ((gg ^ (r & 3)) * 8));
    }
#pragma unroll
    for (int j = 0; j < 4; ++j) {
      int r = w * 64 + j * 16 + rA;
      int sw = (gg ^ (r & 3)) * 8;
      bh[j] = *(const short8v*)(Bhl + r * 32 + sw);
      bl[j] = *(const short8v*)(Bll + r * 32 + sw);
    }
#pragma unroll
    for (int i = 0; i < 4; ++i)
#pragma unroll
      for (int j = 0; j < 4; ++j) {
        acc[i][j] = __builtin_amdgcn_mfma_f32_16x16x32_bf16(af[i], bh[j],
                                                            acc[i][j], 0, 0, 0);
        acc[i][j] = __builtin_amdgcn_mfma_f32_16x16x32_bf16(af[i], bl[j],
                                                            acc[i][j], 0, 0, 0);
      }
    __syncthreads();
  }
  const int cD = l & 15, rD = l >> 4;
  float bj[4], wo[4];
#pragma unroll
  for (int j = 0; j < 4; ++j) {
    int col = w * 64 + j * 16 + cD;
    bj[j] = b2[col];
    wo[j] = W_out[woff + col];
  }
#pragma unroll
  for (int i = 0; i < 4; ++i)
#pragma unroll
    for (int rr = 0; rr < 4; ++rr) {
      float ssv = 0.f, dpv = 0.f;
#pragma unroll
      for (int j = 0; j < 4; ++j) {
        float v = acc[i][j][rr] + bj[j];
        ssv += v * v;
        dpv += v * wo[j];
      }
#pragma unroll
      for (int d = 1; d < 16; d <<= 1) {
        ssv += __shfl_xor(ssv, d);
        dpv += __shfl_xor(dpv, d);
      }
      if (cD == 0) {
        int row = i * 16 + rD * 4 + rr;
        sred[w][row][0] = ssv;
        sred[w][row][1] = dpv;
      }
    }
  __syncthreads();
  if (t < 64) {
    float ss = (sred[0][t][0] + sred[1][t][0]) + (sred[2][t][0] + sred[3][t][0]);
    float dp = (sred[0][t][1] + sred[1][t][1]) + (sred[2][t][1] + sred[3][t][1]);
    outP[row0 + t] = dp / fmaxf(sqrtf(ss), 1e-12f);
  }
}

// ---------------- combine halves + bias ----------------
__global__ __launch_bounds__(256) void k_out2(const float* __restrict__ outP,
                                              const float* __restrict__ b_out,
                                              float* __restrict__ out) {
  int s = blockIdx.x * 256 + threadIdx.x;
  if (s < BS) out[s] = outP[s] + outP[s + BS] + b_out[0];
}

extern "C" void kernel_launch(void* const* d_in, const int* in_sizes, int n_in,
                              void* d_out, int out_size, void* d_ws,
                              size_t ws_size, hipStream_t stream) {
  (void)in_sizes; (void)n_in; (void)out_size; (void)ws_size;
  const float* x_i = (const float*)d_in[0];
  const float* x_j = (const float*)d_in[1];
  const int* src_i = (const int*)d_in[2];
  const int* dst_i = (const int*)d_in[3];
  const int* src_j = (const int*)d_in[4];
  const int* dst_j = (const int*)d_in[5];
  const int* ids_i = (const int*)d_in[6];
  const int* ids_j = (const int*)d_in[7];
  const float* Wn1 = (const float*)d_in[8];
  const float* Ws1 = (const float*)d_in[9];
  const float* b1 = (const float*)d_in[10];
  const float* Wn2 = (const float*)d_in[11];
  const float* Ws2 = (const float*)d_in[12];
  const float* b2 = (const float*)d_in[13];
  const float* W_out = (const float*)d_in[14];
  const float* b_out = (const float*)d_in[15];
  float* out = (float*)d_out;

  char* w = (char*)d_ws;
  int* bcnt       = (int*)(w + 0);            // 1,568
  int* cnt2       = (int*)(w + 4096);         // 401,408
  int* row_start2 = (int*)(w + 405504);       // 401,408
  int* bucketbuf  = (int*)(w + 806912);       // 12,845,056 -> 13,651,968
  ushort* Wt      = (ushort*)(w + 13651968);  // 131,072
  ushort* W2hi    = (ushort*)(w + 13783040);  // 262,144
  ushort* W2lo    = (ushort*)(w + 14045184);  // 262,144
  ushort* xb2     = (ushort*)(w + 14307328);  // 25,600,000 -> 39,907,328
  ushort* aggb2   = (ushort*)(w + 39907328);  // 25,600,000 -> 65,507,328
  ushort* h1b2    = (ushort*)(w + 65507328);  // 51,200,000 -> 116,707,328
  int* csr        = (int*)(w + 116707328);    // 6,400,000 -> 123,107,328
  // aliases over xb2 (dead after k_gemm1):
  ushort* A2      = (ushort*)(w + 14307328);  // 16,777,216 -> 31,084,544
  float* outP     = (float*)(w + 31084544);   // 65,536

  hipMemsetAsync(bcnt, 0, 2 * NBKT * sizeof(int), stream);
  k_prep_bin<<<964, 256, 0, stream>>>(Wn1, Ws1, Wn2, Ws2, Wt, W2hi, W2lo,
                                      src_i, dst_i, src_j, dst_j, bcnt,
                                      bucketbuf);
  k_build_cvt<<<12892, 256, 0, stream>>>(bucketbuf, bcnt, csr, cnt2,
                                         row_start2, x_i, x_j, xb2);
  k_agg1<<<12500, 256, 0, stream>>>(xb2, csr, row_start2, cnt2, aggb2);
  k_gemm1<<<784, 256, 0, stream>>>(aggb2, xb2, Wt, b1, h1b2);
  k_agg2<<<2 * BS, 256, 0, stream>>>(h1b2, csr, row_start2, cnt2, ids_i, ids_j,
                                     A2);
  k_head<<<256, 256, 0, stream>>>(A2, W2hi, W2lo, b2, W_out, outP);
  k_out2<<<32, 256, 0, stream>>>(outP, b_out, out);
}

// Round 14
// 195.693 us; speedup vs baseline: 1.0477x; 1.0147x over previous
//
#include <hip/hip_runtime.h>

constexpr int NN = 50000;     // nodes per graph
constexpr int NE = 800000;    // edges per graph
constexpr int IND = 128;      // in dim
constexpr int HD = 256;       // hidden
constexpr int BS = 8192;      // seeds per graph
constexpr int NPAD = 50176;   // 196*256, block-aligned padded node count
constexpr int NBKT = 196;     // dst>>8 buckets per graph
constexpr int BCAP = 8192;    // capacity per bucket (mean 4096, sigma 64)

typedef __attribute__((ext_vector_type(8))) short short8v;
typedef __attribute__((ext_vector_type(4))) float floatx4;

__device__ inline ushort f2b(float f) {  // f32 -> bf16 RNE
  unsigned u = __float_as_uint(f);
  unsigned r = (u + 0x7fffu + ((u >> 16) & 1u)) >> 16;
  return (ushort)r;
}
__device__ inline float b2f(ushort b) {
  return __uint_as_float((unsigned)b << 16);
}
// accumulate both bf16 halves of a packed u32 (low elem, high elem)
__device__ __forceinline__ void acc2(unsigned u, float& a0, float& a1) {
  a0 += __uint_as_float(u << 16);
  a1 += __uint_as_float(u & 0xffff0000u);
}
__device__ inline int wave_incl_scan(int x, int lane) {
#pragma unroll
  for (int d = 1; d < 64; d <<= 1) {
    int y = __shfl_up(x, d);
    if (lane >= d) x += y;
  }
  return x;
}

// async global->LDS, 16B per lane, wave-uniform LDS base
__device__ __forceinline__ void gload16(const ushort* g, ushort* l) {
  __builtin_amdgcn_global_load_lds(
      (const __attribute__((address_space(1))) void*)g,
      (__attribute__((address_space(3))) void*)l, 16, 0, 0);
}

// ---------------- fused prep + bin + tobf16 (independent block ranges) -------
__global__ __launch_bounds__(256) void k_bin_cvt(
    const float* __restrict__ Wn1, const float* __restrict__ Ws1,
    const float* __restrict__ Wn2, const float* __restrict__ Ws2,
    ushort* __restrict__ Wt, ushort* __restrict__ Whi,
    ushort* __restrict__ Wlo, const int* __restrict__ src_i,
    const int* __restrict__ dst_i, const int* __restrict__ src_j,
    const int* __restrict__ dst_j, int* __restrict__ bcnt,
    int* __restrict__ bucketbuf, const float* __restrict__ x_i,
    const float* __restrict__ x_j, ushort* __restrict__ xb2) {
  __shared__ int hist[NBKT], gbase[NBKT], lcur[NBKT];
  const int b = blockIdx.x, t = threadIdx.x;
  if (b < 256) {  // W1 pack
    int i = b * 256 + t;
    int n = i >> 8, k = i & 255;
    float v = (k < 128) ? Wn1[k * HD + n] : Ws1[(k - 128) * HD + n];
    Wt[n * 256 + k] = f2b(v);
    return;
  }
  if (b < 768) {  // W2 hi/lo split
    int i = (b - 256) * 256 + t;
    int n = i >> 9, k = i & 511;
    float v = (k < 256) ? Wn2[k * HD + n] : Ws2[(k - 256) * HD + n];
    ushort hi = f2b(v);
    Whi[n * 512 + k] = hi;
    Wlo[n * 512 + k] = f2b(v - b2f(hi));
    return;
  }
  if (b >= 964) {  // f32 -> bf16
    int i = (b - 964) * 256 + t;
    int e4 = i * 4;
    int g = e4 >= NN * IND;
    const float* xp = g ? x_j : x_i;
    float4 v = *(const float4*)(xp + (e4 - g * NN * IND));
    ushort4 u;
    u.x = f2b(v.x); u.y = f2b(v.y); u.z = f2b(v.z); u.w = f2b(v.w);
    *(ushort4*)(xb2 + e4) = u;
    return;
  }
  // bin: blocks 768..963
  const int blk = b - 768;
  const int g = blk >= 98;
  const int c = blk - g * 98;
  const int* src = g ? src_j : src_i;
  const int* dst = g ? dst_j : dst_i;
  if (t < NBKT) hist[t] = 0;
  __syncthreads();
  const int e0 = c * 8192;
#pragma unroll
  for (int k = 0; k < 32; ++k) {
    int e = e0 + k * 256 + t;
    if (e < NE) atomicAdd(&hist[dst[e] >> 8], 1);
  }
  __syncthreads();
  if (t < NBKT) {
    int h = hist[t];
    gbase[t] = h ? atomicAdd(&bcnt[g * NBKT + t], h) : 0;
    lcur[t] = 0;
  }
  __syncthreads();
#pragma unroll
  for (int k = 0; k < 32; ++k) {
    int e = e0 + k * 256 + t;
    if (e < NE) {
      int d = dst[e];
      int bk = d >> 8;
      int p = gbase[bk] + atomicAdd(&lcur[bk], 1);
      if (p < BCAP)
        bucketbuf[(g * NBKT + bk) * BCAP + p] = (src[e] << 8) | (d & 255);
    }
  }
}

// ---------------- per-bucket CSR build (bucket-base scan inlined) ------------
__global__ __launch_bounds__(256) void k_build(const int* __restrict__ bucketbuf,
                                               const int* __restrict__ bcnt,
                                               int* __restrict__ csr,
                                               int* __restrict__ cnt2,
                                               int* __restrict__ row_start2) {
  __shared__ int hist[256], lcur[256];
  __shared__ int stage[BCAP];
  __shared__ int wtv[4];
  __shared__ int carry, tot, baseSh;
  const int b = blockIdx.x;
  const int g = b >= NBKT;
  const int bb = b - g * NBKT;
  const int t = threadIdx.x, lane = t & 63;
  if (t == 0) carry = 0;
  __syncthreads();
  for (int ch = 0; ch < 2; ++ch) {
    int i = ch * 256 + t;
    int v = (i < 2 * NBKT) ? min(bcnt[i], BCAP) : 0;
    int x = wave_incl_scan(v, lane);
    if (lane == 63) wtv[t >> 6] = x;
    __syncthreads();
    if (t == 0) {
      int run = 0;
#pragma unroll
      for (int j = 0; j < 4; ++j) { int tv = wtv[j]; wtv[j] = run; run += tv; }
      tot = run;
    }
    __syncthreads();
    if (i == b) baseSh = carry + x - v + wtv[t >> 6];
    __syncthreads();
    if (t == 0) carry += tot;
    __syncthreads();
  }
  const int base = baseSh;
  const int C = min(bcnt[b], BCAP);
  const int* buf = bucketbuf + b * BCAP;
  hist[t] = 0;
  __syncthreads();
  for (int i = t; i < C; i += 256) atomicAdd(&hist[buf[i] & 255], 1);
  __syncthreads();
  int v = hist[t];
  int x = wave_incl_scan(v, lane);
  if (lane == 63) wtv[t >> 6] = x;
  __syncthreads();
  if (t == 0) {
    int run = 0;
#pragma unroll
    for (int j = 0; j < 4; ++j) { int tv = wtv[j]; wtv[j] = run; run += tv; }
  }
  __syncthreads();
  int ls = x - v + wtv[t >> 6];
  lcur[t] = ls;
  __syncthreads();
  for (int i = t; i < C; i += 256) {
    int val = buf[i];
    int p = atomicAdd(&lcur[val & 255], 1);
    stage[p] = val >> 8;
  }
  __syncthreads();
  for (int i = t; i < C; i += 256) csr[base + i] = stage[i];
  int node = bb * 256 + t;
  cnt2[g * NPAD + node] = v;
  row_start2[g * NPAD + node] = base + ls;
}

// ---------------- layer-1 pull aggregation: 2 nodes/wave, dual-chain ILP ------
__global__ __launch_bounds__(256) void k_agg1(const ushort* __restrict__ xb2,
                                              const int* __restrict__ csr,
                                              const int* __restrict__ row_start2,
                                              const int* __restrict__ cnt2,
                                              ushort* __restrict__ aggb2) {
  int w = threadIdx.x >> 6, l = threadIdx.x & 63;
  int p = blockIdx.x * 4 + w;  // pair index, < 50000
  int nA = p * 2;              // NN even -> pair never crosses graph boundary
  int g = nA >= NN;
  int nl = nA - g * NN;
  int base = g * NPAD + nl;
  int stA = row_start2[base], degA = cnt2[base];
  int stB = row_start2[base + 1], degB = cnt2[base + 1];
  const ushort* xb = xb2 + g * NN * IND;
  float a0A = 0.f, a1A = 0.f, a0B = 0.f, a1B = 0.f;
  int cmn = min(degA, degB);
  int e = 0;
  for (; e + 4 <= cmn; e += 4) {
    int sA0 = csr[stA + e + 0], sA1 = csr[stA + e + 1];
    int sA2 = csr[stA + e + 2], sA3 = csr[stA + e + 3];
    int sB0 = csr[stB + e + 0], sB1 = csr[stB + e + 1];
    int sB2 = csr[stB + e + 2], sB3 = csr[stB + e + 3];
    unsigned uA0 = *(const unsigned*)(xb + sA0 * IND + 2 * l);
    unsigned uA1 = *(const unsigned*)(xb + sA1 * IND + 2 * l);
    unsigned uA2 = *(const unsigned*)(xb + sA2 * IND + 2 * l);
    unsigned uA3 = *(const unsigned*)(xb + sA3 * IND + 2 * l);
    unsigned uB0 = *(const unsigned*)(xb + sB0 * IND + 2 * l);
    unsigned uB1 = *(const unsigned*)(xb + sB1 * IND + 2 * l);
    unsigned uB2 = *(const unsigned*)(xb + sB2 * IND + 2 * l);
    unsigned uB3 = *(const unsigned*)(xb + sB3 * IND + 2 * l);
    acc2(uA0, a0A, a1A); acc2(uA1, a0A, a1A);
    acc2(uA2, a0A, a1A); acc2(uA3, a0A, a1A);
    acc2(uB0, a0B, a1B); acc2(uB1, a0B, a1B);
    acc2(uB2, a0B, a1B); acc2(uB3, a0B, a1B);
  }
  int eA = e, eB = e;
  for (; eA + 4 <= degA; eA += 4) {
    int s0 = csr[stA + eA + 0], s1 = csr[stA + eA + 1];
    int s2 = csr[stA + eA + 2], s3 = csr[stA + eA + 3];
    unsigned u0 = *(const unsigned*)(xb + s0 * IND + 2 * l);
    unsigned u1 = *(const unsigned*)(xb + s1 * IND + 2 * l);
    unsigned u2 = *(const unsigned*)(xb + s2 * IND + 2 * l);
    unsigned u3 = *(const unsigned*)(xb + s3 * IND + 2 * l);
    acc2(u0, a0A, a1A); acc2(u1, a0A, a1A);
    acc2(u2, a0A, a1A); acc2(u3, a0A, a1A);
  }
  for (; eA < degA; ++eA) {
    int s = csr[stA + eA];
    unsigned u = *(const unsigned*)(xb + s * IND + 2 * l);
    acc2(u, a0A, a1A);
  }
  for (; eB + 4 <= degB; eB += 4) {
    int s0 = csr[stB + eB + 0], s1 = csr[stB + eB + 1];
    int s2 = csr[stB + eB + 2], s3 = csr[stB + eB + 3];
    unsigned u0 = *(const unsigned*)(xb + s0 * IND + 2 * l);
    unsigned u1 = *(const unsigned*)(xb + s1 * IND + 2 * l);
    unsigned u2 = *(const unsigned*)(xb + s2 * IND + 2 * l);
    unsigned u3 = *(const unsigned*)(xb + s3 * IND + 2 * l);
    acc2(u0, a0B, a1B); acc2(u1, a0B, a1B);
    acc2(u2, a0B, a1B); acc2(u3, a0B, a1B);
  }
  for (; eB < degB; ++eB) {
    int s = csr[stB + eB];
    unsigned u = *(const unsigned*)(xb + s * IND + 2 * l);
    acc2(u, a0B, a1B);
  }
  float invA = 1.f / (float)max(degA, 1);
  float invB = 1.f / (float)max(degB, 1);
  ushort2 uA, uB;
  uA.x = f2b(a0A * invA); uA.y = f2b(a1A * invA);
  uB.x = f2b(a0B * invB); uB.y = f2b(a1B * invB);
  *(ushort2*)(aggb2 + (g * NN + nl) * IND + 2 * l) = uA;
  *(ushort2*)(aggb2 + (g * NN + nl + 1) * IND + 2 * l) = uB;
}

// ---------------- layer-1 MFMA GEMM: h1b = relu([agg|x] @ [Wn1;Ws1] + b1) ----
// BM=128, BN=256 (full N, A read once), BK=32; grid 784; 4 waves 2x2
__global__ __launch_bounds__(256) void k_gemm1(const ushort* __restrict__ aggb2,
                                               const ushort* __restrict__ xb2,
                                               const ushort* __restrict__ Wt,
                                               const float* __restrict__ b1,
                                               ushort* __restrict__ h1b2) {
  __shared__ ushort smem[32768];  // dbuf: A 2x4096 | B 2x8192 (48KB); epi: 128x256
  const int t = threadIdx.x;
  const int g = blockIdx.x >= 392;
  const int row0 = (blockIdx.x - g * 392) * 128;
  const ushort* aggb = aggb2 + g * NN * IND;
  const ushort* xb = xb2 + g * NN * IND;
  ushort* h1b = h1b2 + g * NN * HD;
  const int w = t >> 6, l = t & 63;
  const int wm = w & 1, wn = w >> 1;

  const int r0 = t >> 2, cs0 = t & 3;
  const int c0 = cs0 ^ (r0 & 3);
  const int rA0 = min(row0 + r0, NN - 1);
  const int rA1 = min(row0 + r0 + 64, NN - 1);
  const int gA0 = rA0 * IND + c0 * 8;
  const int gA1 = rA1 * IND + c0 * 8;
  const int gB0 = (r0 + 0) * 256 + c0 * 8;
  const int gB1 = (r0 + 64) * 256 + c0 * 8;
  const int gB2 = (r0 + 128) * 256 + c0 * 8;
  const int gB3 = (r0 + 192) * 256 + c0 * 8;
  const int wofs = w * 512;

  floatx4 acc[4][8];
#pragma unroll
  for (int i = 0; i < 4; ++i)
#pragma unroll
    for (int j = 0; j < 8; ++j) acc[i][j] = (floatx4){0.f, 0.f, 0.f, 0.f};

#define STAGE(buf, kk)                                                      \
  do {                                                                      \
    const ushort* Ab = ((kk) < 128) ? (aggb + (kk)) : (xb + ((kk) - 128));  \
    ushort* Ald = smem + (buf) * 4096;                                      \
    ushort* Bld = smem + 8192 + (buf) * 8192;                               \
    gload16(Ab + gA0, Ald + wofs);                                          \
    gload16(Ab + gA1, Ald + 2048 + wofs);                                   \
    gload16(Wt + gB0 + (kk), Bld + wofs);                                   \
    gload16(Wt + gB1 + (kk), Bld + 2048 + wofs);                            \
    gload16(Wt + gB2 + (kk), Bld + 4096 + wofs);                            \
    gload16(Wt + gB3 + (kk), Bld + 6144 + wofs);                            \
  } while (0)

  STAGE(0, 0);
  __syncthreads();
  int cur = 0;
  const int rA = l & 15, gg = l >> 4;
  for (int step = 0; step < 8; ++step) {
    if (step < 7) STAGE(cur ^ 1, (step + 1) * 32);
    const ushort* Abuf = smem + cur * 4096;
    const ushort* Bbuf = smem + 8192 + cur * 8192;
    short8v af[4], bf[8];
#pragma unroll
    for (int i = 0; i < 4; ++i) {
      int r = wm * 64 + i * 16 + rA;
      af[i] = *(const short8v*)(Abuf + r * 32 + ((gg ^ (r & 3)) * 8));
    }
#pragma unroll
    for (int j = 0; j < 8; ++j) {
      int r = wn * 128 + j * 16 + rA;
      bf[j] = *(const short8v*)(Bbuf + r * 32 + ((gg ^ (r & 3)) * 8));
    }
#pragma unroll
    for (int i = 0; i < 4; ++i)
#pragma unroll
      for (int j = 0; j < 8; ++j)
        acc[i][j] = __builtin_amdgcn_mfma_f32_16x16x32_bf16(af[i], bf[j],
                                                            acc[i][j], 0, 0, 0);
    if (step < 7) {
      __syncthreads();
      cur ^= 1;
    }
  }
#undef STAGE

  // epilogue: acc -> bf16 LDS tile [128][256], then coalesced row stores
  __syncthreads();
  const int rD = l >> 4, cD = l & 15;
#pragma unroll
  for (int j = 0; j < 8; ++j) {
    int cl = wn * 128 + j * 16 + cD;
    float bias = b1[cl];
#pragma unroll
    for (int i = 0; i < 4; ++i) {
      int rbase = wm * 64 + i * 16 + rD * 4;
#pragma unroll
      for (int rr = 0; rr < 4; ++rr)
        smem[(rbase + rr) * 256 + cl] = f2b(fmaxf(acc[i][j][rr] + bias, 0.f));
    }
  }
  __syncthreads();
  const int rl = t >> 5, ch = t & 31;
#pragma unroll
  for (int it = 0; it < 16; ++it) {
    int row_l = rl + it * 8;
    int grow = row0 + row_l;
    if (grow < NN)
      *(short8v*)(h1b + grow * HD + ch * 8) =
          *(const short8v*)(smem + row_l * 256 + ch * 8);
  }
}

// ---------------- layer-2 aggregation @ seeds: half-wave, 2 edges/instr ------
__global__ __launch_bounds__(256) void k_agg2(
    const ushort* __restrict__ h1b2, const int* __restrict__ csr,
    const int* __restrict__ row_start2, const int* __restrict__ cnt2,
    const int* __restrict__ ids_i, const int* __restrict__ ids_j,
    ushort* __restrict__ A2) {
  __shared__ float red[4][HD];
  const int b = blockIdx.x;
  const int g = b >= BS;
  const int node = (g ? ids_j : ids_i)[b - g * BS];
  const int st = row_start2[g * NPAD + node], deg = cnt2[g * NPAD + node];
  const ushort* h1b = h1b2 + g * NN * HD;
  const int w = threadIdx.x >> 6, l = threadIdx.x & 63;
  const int h = l >> 5, c = l & 31;
  float a0 = 0.f, a1 = 0.f, a2 = 0.f, a3 = 0.f;
  float a4 = 0.f, a5 = 0.f, a6 = 0.f, a7 = 0.f;
  int e = w * 2 + h;
  for (; e + 8 < deg; e += 16) {
    int s0 = csr[st + e], s1 = csr[st + e + 8];
    uint4 u0 = *(const uint4*)(h1b + s0 * HD + c * 8);
    uint4 u1 = *(const uint4*)(h1b + s1 * HD + c * 8);
    acc2(u0.x, a0, a1); acc2(u0.y, a2, a3);
    acc2(u0.z, a4, a5); acc2(u0.w, a6, a7);
    acc2(u1.x, a0, a1); acc2(u1.y, a2, a3);
    acc2(u1.z, a4, a5); acc2(u1.w, a6, a7);
  }
  if (e < deg) {
    int s = csr[st + e];
    uint4 u = *(const uint4*)(h1b + s * HD + c * 8);
    acc2(u.x, a0, a1); acc2(u.y, a2, a3);
    acc2(u.z, a4, a5); acc2(u.w, a6, a7);
  }
  a0 += __shfl_xor(a0, 32); a1 += __shfl_xor(a1, 32);
  a2 += __shfl_xor(a2, 32); a3 += __shfl_xor(a3, 32);
  a4 += __shfl_xor(a4, 32); a5 += __shfl_xor(a5, 32);
  a6 += __shfl_xor(a6, 32); a7 += __shfl_xor(a7, 32);
  if (h == 0) {
    *(float4*)&red[w][c * 8] = (float4){a0, a1, a2, a3};
    *(float4*)&red[w][c * 8 + 4] = (float4){a4, a5, a6, a7};
  }
  __syncthreads();
  const int t = threadIdx.x;
  float s = (red[0][t] + red[1][t]) + (red[2][t] + red[3][t]);
  s *= 1.f / (float)max(deg, 1);
  A2[b * 512 + t] = f2b(s);
  A2[b * 512 + 256 + t] = h1b[node * HD + t];  // exact bf16 copy
}

// ---------------- layer-2 MFMA GEMM + fused l2norm/dot -> outP --------------
// 64 rows x 256 cols per block, K=512; grid 256
__global__ __launch_bounds__(256) void k_head(const ushort* __restrict__ A2,
                                              const ushort* __restrict__ Whi,
                                              const ushort* __restrict__ Wlo,
                                              const float* __restrict__ b2,
                                              const float* __restrict__ W_out,
                                              float* __restrict__ outP) {
  __shared__ ushort Ahl[64 * 32];
  __shared__ ushort Bhl[256 * 32];
  __shared__ ushort Bll[256 * 32];
  __shared__ float sred[4][64][2];
  const int t = threadIdx.x;
  const int row0 = blockIdx.x * 64;
  const int w = t >> 6, l = t & 63;
  const int woff = (row0 >= BS) ? 256 : 0;
  floatx4 acc[4][4];
#pragma unroll
  for (int i = 0; i < 4; ++i)
#pragma unroll
    for (int j = 0; j < 4; ++j) acc[i][j] = (floatx4){0.f, 0.f, 0.f, 0.f};

  for (int kk = 0; kk < 512; kk += 32) {
    {
      int r = t >> 2, c = t & 3;
      int sw = (c ^ (r & 3)) * 8;
      *(short8v*)(Ahl + r * 32 + sw) =
          *(const short8v*)(A2 + (row0 + r) * 512 + kk + c * 8);
    }
#pragma unroll
    for (int s = t; s < 1024; s += 256) {
      int r = s >> 2, c = s & 3;
      int sw = (c ^ (r & 3)) * 8;
      *(short8v*)(Bhl + r * 32 + sw) =
          *(const short8v*)(Whi + r * 512 + kk + c * 8);
      *(short8v*)(Bll + r * 32 + sw) =
          *(const short8v*)(Wlo + r * 512 + kk + c * 8);
    }
    __syncthreads();
    const int rA = l & 15, gg = l >> 4;
    short8v af[4], bh[4], bl[4];
#pragma unroll
    for (int i = 0; i < 4; ++i) {
      int r = i * 16 + rA;
      af[i] = *(const short8v*)(Ahl + r * 32 + ((gg ^ (r & 3)) * 8));
    }
#pragma unroll
    for (int j = 0; j < 4; ++j) {
      int r = w * 64 + j * 16 + rA;
      int sw = (gg ^ (r & 3)) * 8;
      bh[j] = *(const short8v*)(Bhl + r * 32 + sw);
      bl[j] = *(const short8v*)(Bll + r * 32 + sw);
    }
#pragma unroll
    for (int i = 0; i < 4; ++i)
#pragma unroll
      for (int j = 0; j < 4; ++j) {
        acc[i][j] = __builtin_amdgcn_mfma_f32_16x16x32_bf16(af[i], bh[j],
                                                            acc[i][j], 0, 0, 0);
        acc[i][j] = __builtin_amdgcn_mfma_f32_16x16x32_bf16(af[i], bl[j],
                                                            acc[i][j], 0, 0, 0);
      }
    __syncthreads();
  }
  const int cD = l & 15, rD = l >> 4;
  float bj[4], wo[4];
#pragma unroll
  for (int j = 0; j < 4; ++j) {
    int col = w * 64 + j * 16 + cD;
    bj[j] = b2[col];
    wo[j] = W_out[woff + col];
  }
#pragma unroll
  for (int i = 0; i < 4; ++i)
#pragma unroll
    for (int rr = 0; rr < 4; ++rr) {
      float ssv = 0.f, dpv = 0.f;
#pragma unroll
      for (int j = 0; j < 4; ++j) {
        float v = acc[i][j][rr] + bj[j];
        ssv += v * v;
        dpv += v * wo[j];
      }
#pragma unroll
      for (int d = 1; d < 16; d <<= 1) {
        ssv += __shfl_xor(ssv, d);
        dpv += __shfl_xor(dpv, d);
      }
      if (cD == 0) {
        int row = i * 16 + rD * 4 + rr;
        sred[w][row][0] = ssv;
        sred[w][row][1] = dpv;
      }
    }
  __syncthreads();
  if (t < 64) {
    float ss = (sred[0][t][0] + sred[1][t][0]) + (sred[2][t][0] + sred[3][t][0]);
    float dp = (sred[0][t][1] + sred[1][t][1]) + (sred[2][t][1] + sred[3][t][1]);
    outP[row0 + t] = dp / fmaxf(sqrtf(ss), 1e-12f);
  }
}

// ---------------- combine halves + bias ----------------
__global__ __launch_bounds__(256) void k_out2(const float* __restrict__ outP,
                                              const float* __restrict__ b_out,
                                              float* __restrict__ out) {
  int s = blockIdx.x * 256 + threadIdx.x;
  if (s < BS) out[s] = outP[s] + outP[s + BS] + b_out[0];
}

extern "C" void kernel_launch(void* const* d_in, const int* in_sizes, int n_in,
                              void* d_out, int out_size, void* d_ws,
                              size_t ws_size, hipStream_t stream) {
  (void)in_sizes; (void)n_in; (void)out_size; (void)ws_size;
  const float* x_i = (const float*)d_in[0];
  const float* x_j = (const float*)d_in[1];
  const int* src_i = (const int*)d_in[2];
  const int* dst_i = (const int*)d_in[3];
  const int* src_j = (const int*)d_in[4];
  const int* dst_j = (const int*)d_in[5];
  const int* ids_i = (const int*)d_in[6];
  const int* ids_j = (const int*)d_in[7];
  const float* Wn1 = (const float*)d_in[8];
  const float* Ws1 = (const float*)d_in[9];
  const float* b1 = (const float*)d_in[10];
  const float* Wn2 = (const float*)d_in[11];
  const float* Ws2 = (const float*)d_in[12];
  const float* b2 = (const float*)d_in[13];
  const float* W_out = (const float*)d_in[14];
  const float* b_out = (const float*)d_in[15];
  float* out = (float*)d_out;

  char* w = (char*)d_ws;
  int* bcnt       = (int*)(w + 0);            // 1,568
  int* cnt2       = (int*)(w + 4096);         // 401,408
  int* row_start2 = (int*)(w + 405504);       // 401,408
  int* bucketbuf  = (int*)(w + 806912);       // 12,845,056 -> 13,651,968
  ushort* Wt      = (ushort*)(w + 13651968);  // 131,072
  ushort* W2hi    = (ushort*)(w + 13783040);  // 262,144
  ushort* W2lo    = (ushort*)(w + 14045184);  // 262,144
  ushort* xb2     = (ushort*)(w + 14307328);  // 25,600,000 -> 39,907,328
  ushort* aggb2   = (ushort*)(w + 39907328);  // 25,600,000 -> 65,507,328
  ushort* h1b2    = (ushort*)(w + 65507328);  // 51,200,000 -> 116,707,328
  int* csr        = (int*)(w + 116707328);    // 6,400,000 -> 123,107,328
  // aliases over xb2 (dead after k_gemm1):
  ushort* A2      = (ushort*)(w + 14307328);  // 16,777,216 -> 31,084,544
  float* outP     = (float*)(w + 31084544);   // 65,536

  hipMemsetAsync(bcnt, 0, 2 * NBKT * sizeof(int), stream);
  k_bin_cvt<<<13464, 256, 0, stream>>>(Wn1, Ws1, Wn2, Ws2, Wt, W2hi, W2lo,
                                       src_i, dst_i, src_j, dst_j, bcnt,
                                       bucketbuf, x_i, x_j, xb2);
  k_build<<<392, 256, 0, stream>>>(bucketbuf, bcnt, csr, cnt2, row_start2);
  k_agg1<<<12500, 256, 0, stream>>>(xb2, csr, row_start2, cnt2, aggb2);
  k_gemm1<<<784, 256, 0, stream>>>(aggb2, xb2, Wt, b1, h1b2);
  k_agg2<<<2 * BS, 256, 0, stream>>>(h1b2, csr, row_start2, cnt2, ids_i, ids_j,
                                     A2);
  k_head<<<256, 256, 0, stream>>>(A2, W2hi, W2lo, b2, W_out, outP);
  k_out2<<<32, 256, 0, stream>>>(outP, b_out, out);
}